// Round 1
// baseline (215.991 us; speedup 1.0000x reference)
//
#include <hip/hip_runtime.h>
#include <hip/hip_bf16.h>

typedef __bf16 bf16_t;
typedef __bf16 bf16x8 __attribute__((ext_vector_type(8)));
typedef float  f32x4  __attribute__((ext_vector_type(4)));

#define NB 8
#define NN 1024
#define NC 1024
#define NH 16
#define ND 64
// B*H
#define NBH 128

__device__ __forceinline__ void gload_lds16(const bf16_t* g, bf16_t* l) {
  __builtin_amdgcn_global_load_lds(
      (const __attribute__((address_space(1))) void*)g,
      (__attribute__((address_space(3))) void*)l, 16, 0, 0);
}

// ---------------- cast f32 -> bf16 (contiguous), n = grid*256*8 ----------------
__global__ void cast_f32_bf16_k(const float* __restrict__ src, bf16_t* __restrict__ dst) {
  size_t i = ((size_t)blockIdx.x * blockDim.x + threadIdx.x) * 8;
  float4 f0 = *(const float4*)(src + i);
  float4 f1 = *(const float4*)(src + i + 4);
  bf16x8 o;
  o[0]=(bf16_t)f0.x; o[1]=(bf16_t)f0.y; o[2]=(bf16_t)f0.z; o[3]=(bf16_t)f0.w;
  o[4]=(bf16_t)f1.x; o[5]=(bf16_t)f1.y; o[6]=(bf16_t)f1.z; o[7]=(bf16_t)f1.w;
  *(bf16x8*)(dst + i) = o;
}

// ---------------- build V^T: x[b][n][h*64+d] -> Vt[bh][d][n] (bf16) ----------------
// grid: (NN/64, NBH), block 256
__global__ void build_vt_k(const float* __restrict__ x, bf16_t* __restrict__ vt) {
  const int j = blockIdx.x, bh = blockIdx.y;
  const int b = bh >> 4, h = bh & 15;
  __shared__ bf16_t T[64][65];
  const int t = threadIdx.x;
  {
    const int mm = t >> 2, ds = (t & 3) * 16;
    const float* src = x + ((size_t)((b << 10) + (j << 6) + mm)) * NC + (h << 6) + ds;
    #pragma unroll
    for (int e = 0; e < 16; e += 4) {
      float4 f = *(const float4*)(src + e);
      T[mm][ds + e + 0] = (bf16_t)f.x;
      T[mm][ds + e + 1] = (bf16_t)f.y;
      T[mm][ds + e + 2] = (bf16_t)f.z;
      T[mm][ds + e + 3] = (bf16_t)f.w;
    }
  }
  __syncthreads();
  {
    const int d = t >> 2, ms = (t & 3) * 16;
    bf16_t* dstp = vt + (size_t)bh * (ND * NN) + (size_t)d * NN + (j << 6) + ms;
    bf16x8 o0, o1;
    #pragma unroll
    for (int e = 0; e < 8; ++e) { o0[e] = T[ms + e][d]; o1[e] = T[ms + 8 + e][d]; }
    *(bf16x8*)(dstp) = o0;
    *(bf16x8*)(dstp + 8) = o1;
  }
}

// ---------------- GEMM: C[m][n] = A[m][:]·Bw[n][:] + bias[n] -> Q/K bf16 ----------------
// A: [8192][1024] bf16, Bw: [2048][1024] bf16. grid (2048/128=16, 8192/128=64), block 256.
__global__ __launch_bounds__(256) void gemm_qk_k(
    const bf16_t* __restrict__ A, const bf16_t* __restrict__ Bw,
    const float* __restrict__ bias, bf16_t* __restrict__ Qg, bf16_t* __restrict__ Kg) {
  __shared__ bf16_t As[128 * 32];
  __shared__ bf16_t Bs[128 * 32];
  const int tid = threadIdx.x;
  const int w = tid >> 6, lane = tid & 63;
  const int wr = w >> 1, wc = w & 1;
  const int il = lane & 15, g = lane >> 4;
  const int rowBase = blockIdx.y * 128;
  const int colBase = blockIdx.x * 128;

  f32x4 acc[4][4];
  #pragma unroll
  for (int i = 0; i < 4; ++i)
    #pragma unroll
    for (int j = 0; j < 4; ++j) acc[i][j] = (f32x4){0.f, 0.f, 0.f, 0.f};

  for (int k0 = 0; k0 < 1024; k0 += 32) {
    __syncthreads();
    #pragma unroll
    for (int inst = 0; inst < 2; ++inst) {
      const int u = inst * 256 + w * 64 + lane;
      const int row = u >> 2, kb = (u & 3) * 8;
      gload_lds16(A  + (size_t)(rowBase + row) * 1024 + k0 + kb, &As[(inst * 256 + w * 64) * 8]);
      gload_lds16(Bw + (size_t)(colBase + row) * 1024 + k0 + kb, &Bs[(inst * 256 + w * 64) * 8]);
    }
    __syncthreads();
    bf16x8 a[4], bb[4];
    #pragma unroll
    for (int i = 0; i < 4; ++i) a[i]  = *(const bf16x8*)&As[(wr * 64 + i * 16 + il) * 32 + 8 * g];
    #pragma unroll
    for (int j = 0; j < 4; ++j) bb[j] = *(const bf16x8*)&Bs[(wc * 64 + j * 16 + il) * 32 + 8 * g];
    #pragma unroll
    for (int i = 0; i < 4; ++i)
      #pragma unroll
      for (int j = 0; j < 4; ++j)
        acc[i][j] = __builtin_amdgcn_mfma_f32_16x16x32_bf16(a[i], bb[j], acc[i][j], 0, 0, 0);
  }

  // epilogue: route to Q (n<1024) or K (n>=1024), layout [b][h][row][d]
  #pragma unroll
  for (int i = 0; i < 4; ++i) {
    const int mbase = rowBase + wr * 64 + i * 16 + g * 4;
    #pragma unroll
    for (int j = 0; j < 4; ++j) {
      const int n = colBase + wc * 64 + j * 16 + il;
      const float bv = bias[n];
      #pragma unroll
      for (int r = 0; r < 4; ++r) {
        const int mg = mbase + r;
        const int brow = mg >> 10, nrow = mg & 1023;
        const float v = acc[i][j][r] + bv;
        if (n < 1024) {
          const int h = n >> 6, d = n & 63;
          Qg[(((size_t)(brow * 16 + h)) * 1024 + nrow) * 64 + d] = (bf16_t)v;
        } else {
          const int n2 = n - 1024;
          const int h = n2 >> 6, d = n2 & 63;
          Kg[(((size_t)(brow * 16 + h)) * 1024 + nrow) * 64 + d] = (bf16_t)v;
        }
      }
    }
  }
}

// ---------------- causal flash attention + tanh ----------------
// grid (NN/64=16, NBH=128), block 256 (4 waves, 16 q-rows each)
__global__ __launch_bounds__(256) void flash_attn_k(
    const bf16_t* __restrict__ Qg, const bf16_t* __restrict__ Kg,
    const bf16_t* __restrict__ Vt, const float* __restrict__ temperature,
    float* __restrict__ out) {
  const int qb = blockIdx.x, bh = blockIdx.y;
  const int b = bh >> 4, h = bh & 15;
  __shared__ bf16_t Qs[64 * 64];
  __shared__ bf16_t Ks[64 * 64];
  __shared__ bf16_t Vts[64 * 64];
  __shared__ bf16_t Pl[4][16 * 64];
  const int tid = threadIdx.x, w = tid >> 6, lane = tid & 63;
  const int il = lane & 15, g = lane >> 4;
  const float scale = 0.125f / temperature[h];

  // stage Q tile (64x64)
  #pragma unroll
  for (int inst = 0; inst < 2; ++inst) {
    const int u = inst * 256 + w * 64 + lane;
    const int row = u >> 3, ub = u & 7;
    gload_lds16(Qg + ((size_t)bh * 1024 + qb * 64 + row) * 64 + ub * 8,
                &Qs[(inst * 256 + w * 64) * 8]);
  }
  __syncthreads();
  bf16x8 qf0 = *(const bf16x8*)&Qs[(w * 16 + il) * 64 + 8 * g];
  bf16x8 qf1 = *(const bf16x8*)&Qs[(w * 16 + il) * 64 + 32 + 8 * g];

  float m_run[4], l_run[4];
  f32x4 acc_o[4];
  #pragma unroll
  for (int r = 0; r < 4; ++r) { m_run[r] = -1e30f; l_run[r] = 0.f; }
  #pragma unroll
  for (int td = 0; td < 4; ++td) acc_o[td] = (f32x4){0.f, 0.f, 0.f, 0.f};

  const int q_row_w = qb * 64 + w * 16;

  for (int j = 0; j <= qb; ++j) {
    __syncthreads();
    #pragma unroll
    for (int inst = 0; inst < 2; ++inst) {
      const int u = inst * 256 + w * 64 + lane;
      const int row = u >> 3, ub = u & 7;
      gload_lds16(Kg + ((size_t)bh * 1024 + j * 64 + row) * 64 + ub * 8,
                  &Ks[(inst * 256 + w * 64) * 8]);
      gload_lds16(Vt + (size_t)bh * (ND * NN) + (size_t)row * NN + j * 64 + ub * 8,
                  &Vts[(inst * 256 + w * 64) * 8]);
    }
    __syncthreads();

    // S = Q K^T  (16 x 64 per wave)
    f32x4 s[4];
    #pragma unroll
    for (int t = 0; t < 4; ++t) {
      s[t] = (f32x4){0.f, 0.f, 0.f, 0.f};
      bf16x8 k0 = *(const bf16x8*)&Ks[(t * 16 + il) * 64 + 8 * g];
      bf16x8 k1 = *(const bf16x8*)&Ks[(t * 16 + il) * 64 + 32 + 8 * g];
      s[t] = __builtin_amdgcn_mfma_f32_16x16x32_bf16(qf0, k0, s[t], 0, 0, 0);
      s[t] = __builtin_amdgcn_mfma_f32_16x16x32_bf16(qf1, k1, s[t], 0, 0, 0);
    }

    const bool diag = (j == qb);
    float sv[4][4];   // [t][r]
    #pragma unroll
    for (int t = 0; t < 4; ++t) {
      const int kg = j * 64 + t * 16 + il;
      #pragma unroll
      for (int r = 0; r < 4; ++r) {
        float v = s[t][r] * scale;
        if (diag && kg > q_row_w + g * 4 + r) v = -1e30f;
        sv[t][r] = v;
      }
    }
    // row max (16-lane butterfly within group)
    float mnew[4];
    #pragma unroll
    for (int r = 0; r < 4; ++r) {
      float mx = fmaxf(fmaxf(sv[0][r], sv[1][r]), fmaxf(sv[2][r], sv[3][r]));
      #pragma unroll
      for (int off = 1; off < 16; off <<= 1) mx = fmaxf(mx, __shfl_xor(mx, off, 64));
      mnew[r] = fmaxf(m_run[r], mx);
    }
    // P = exp(S - mnew), row sum, online update
    float pexp[4][4];
    float lsum[4];
    #pragma unroll
    for (int r = 0; r < 4; ++r) {
      float sm = 0.f;
      #pragma unroll
      for (int t = 0; t < 4; ++t) { float p = __expf(sv[t][r] - mnew[r]); pexp[t][r] = p; sm += p; }
      #pragma unroll
      for (int off = 1; off < 16; off <<= 1) sm += __shfl_xor(sm, off, 64);
      lsum[r] = sm;
    }
    #pragma unroll
    for (int r = 0; r < 4; ++r) {
      const float f = __expf(m_run[r] - mnew[r]);
      l_run[r] = l_run[r] * f + lsum[r];
      m_run[r] = mnew[r];
      #pragma unroll
      for (int td = 0; td < 4; ++td) acc_o[td][r] *= f;
    }
    // P -> LDS (bf16, A-fragment source layout [q][m])
    #pragma unroll
    for (int t = 0; t < 4; ++t)
      #pragma unroll
      for (int r = 0; r < 4; ++r)
        Pl[w][(g * 4 + r) * 64 + t * 16 + il] = (bf16_t)pexp[t][r];

    bf16x8 pf0 = *(const bf16x8*)&Pl[w][il * 64 + 8 * g];
    bf16x8 pf1 = *(const bf16x8*)&Pl[w][il * 64 + 32 + 8 * g];
    #pragma unroll
    for (int td = 0; td < 4; ++td) {
      bf16x8 v0 = *(const bf16x8*)&Vts[(td * 16 + il) * 64 + 8 * g];
      bf16x8 v1 = *(const bf16x8*)&Vts[(td * 16 + il) * 64 + 32 + 8 * g];
      acc_o[td] = __builtin_amdgcn_mfma_f32_16x16x32_bf16(pf0, v0, acc_o[td], 0, 0, 0);
      acc_o[td] = __builtin_amdgcn_mfma_f32_16x16x32_bf16(pf1, v1, acc_o[td], 0, 0, 0);
    }
  }

  // epilogue: out = tanh(acc/l), layout [b][n][h*64+d] f32
  #pragma unroll
  for (int td = 0; td < 4; ++td) {
    #pragma unroll
    for (int r = 0; r < 4; ++r) {
      const int qrow = q_row_w + g * 4 + r;
      const int d = td * 16 + il;
      const float o = tanhf(acc_o[td][r] / l_run[r]);
      out[((size_t)b * 1024 + qrow) * 1024 + (h << 6) + d] = o;
    }
  }
}

extern "C" void kernel_launch(void* const* d_in, const int* in_sizes, int n_in,
                              void* d_out, int out_size, void* d_ws, size_t ws_size,
                              hipStream_t stream) {
  const float* z_k  = (const float*)d_in[0];
  const float* x    = (const float*)d_in[1];
  const float* Wqkv = (const float*)d_in[2];
  const float* bqkv = (const float*)d_in[3];
  const float* temp = (const float*)d_in[4];
  float* out = (float*)d_out;

  char* ws = (char*)d_ws;
  // layout (bytes): A 16M, Bw 4M, Qg 16M, Kg 16M, Vt 16M  => 71.3 MB total
  bf16_t* A  = (bf16_t*)(ws);
  bf16_t* Bw = (bf16_t*)(ws + 16777216);
  bf16_t* Qg = (bf16_t*)(ws + 16777216 + 4194304);
  bf16_t* Kg = (bf16_t*)(ws + 16777216 + 4194304 + 16777216);
  bf16_t* Vt = (bf16_t*)(ws + 16777216 + 4194304 + 2 * 16777216);

  cast_f32_bf16_k<<<4096, 256, 0, stream>>>(z_k, A);          // 8192*1024
  cast_f32_bf16_k<<<1024, 256, 0, stream>>>(Wqkv, Bw);        // first 2048 rows
  build_vt_k<<<dim3(16, 128), 256, 0, stream>>>(x, Vt);
  gemm_qk_k<<<dim3(16, 64), 256, 0, stream>>>(A, Bw, bqkv, Qg, Kg);
  flash_attn_k<<<dim3(16, 128), 256, 0, stream>>>(Qg, Kg, Vt, temp, out);
}

// Round 2
// 155.714 us; speedup vs baseline: 1.3871x; 1.3871x over previous
//
#include <hip/hip_runtime.h>
#include <hip/hip_bf16.h>

typedef __bf16 bf16_t;
typedef __bf16 bf16x4 __attribute__((ext_vector_type(4)));
typedef __bf16 bf16x8 __attribute__((ext_vector_type(8)));
typedef float  f32x4  __attribute__((ext_vector_type(4)));

#define NB 8
#define NN 1024
#define NC 1024
#define NH 16
#define ND 64
// B*H
#define NBH 128

__device__ __forceinline__ void gload_lds16(const bf16_t* g, bf16_t* l) {
  __builtin_amdgcn_global_load_lds(
      (const __attribute__((address_space(1))) void*)g,
      (__attribute__((address_space(3))) void*)l, 16, 0, 0);
}

// ---------------- cast f32 -> bf16 (contiguous), n = grid*256*8 ----------------
__global__ void cast_f32_bf16_k(const float* __restrict__ src, bf16_t* __restrict__ dst) {
  size_t i = ((size_t)blockIdx.x * blockDim.x + threadIdx.x) * 8;
  float4 f0 = *(const float4*)(src + i);
  float4 f1 = *(const float4*)(src + i + 4);
  bf16x8 o;
  o[0]=(bf16_t)f0.x; o[1]=(bf16_t)f0.y; o[2]=(bf16_t)f0.z; o[3]=(bf16_t)f0.w;
  o[4]=(bf16_t)f1.x; o[5]=(bf16_t)f1.y; o[6]=(bf16_t)f1.z; o[7]=(bf16_t)f1.w;
  *(bf16x8*)(dst + i) = o;
}

// ---------------- build V^T: x[b][n][h*64+d] -> Vt[bh][d][n] (bf16) ----------------
// grid: (NN/64, NBH), block 256
__global__ void build_vt_k(const float* __restrict__ x, bf16_t* __restrict__ vt) {
  const int j = blockIdx.x, bh = blockIdx.y;
  const int b = bh >> 4, h = bh & 15;
  __shared__ bf16_t T[64][65];
  const int t = threadIdx.x;
  {
    const int mm = t >> 2, ds = (t & 3) * 16;
    const float* src = x + ((size_t)((b << 10) + (j << 6) + mm)) * NC + (h << 6) + ds;
    #pragma unroll
    for (int e = 0; e < 16; e += 4) {
      float4 f = *(const float4*)(src + e);
      T[mm][ds + e + 0] = (bf16_t)f.x;
      T[mm][ds + e + 1] = (bf16_t)f.y;
      T[mm][ds + e + 2] = (bf16_t)f.z;
      T[mm][ds + e + 3] = (bf16_t)f.w;
    }
  }
  __syncthreads();
  {
    const int d = t >> 2, ms = (t & 3) * 16;
    bf16_t* dstp = vt + (size_t)bh * (ND * NN) + (size_t)d * NN + (j << 6) + ms;
    bf16x8 o0, o1;
    #pragma unroll
    for (int e = 0; e < 8; ++e) { o0[e] = T[ms + e][d]; o1[e] = T[ms + 8 + e][d]; }
    *(bf16x8*)(dstp) = o0;
    *(bf16x8*)(dstp + 8) = o1;
  }
}

// ---------------- GEMM: C[m][n] = A[m][:]·Bw[n][:] + bias[n] -> Q/K bf16 ----------------
// A: [8192][1024] bf16, Bw: [2048][1024] bf16. grid (16, 64), block 256.
__global__ __launch_bounds__(256) void gemm_qk_k(
    const bf16_t* __restrict__ A, const bf16_t* __restrict__ Bw,
    const float* __restrict__ bias, bf16_t* __restrict__ Qg, bf16_t* __restrict__ Kg) {
  __shared__ bf16_t As[128 * 32];
  __shared__ bf16_t Bs[128 * 32];
  const int tid = threadIdx.x;
  const int w = tid >> 6, lane = tid & 63;
  const int wr = w >> 1, wc = w & 1;
  const int il = lane & 15, g = lane >> 4;
  const int rowBase = blockIdx.y * 128;
  const int colBase = blockIdx.x * 128;

  f32x4 acc[4][4];
  #pragma unroll
  for (int i = 0; i < 4; ++i)
    #pragma unroll
    for (int j = 0; j < 4; ++j) acc[i][j] = (f32x4){0.f, 0.f, 0.f, 0.f};

  for (int k0 = 0; k0 < 1024; k0 += 32) {
    __syncthreads();
    #pragma unroll
    for (int inst = 0; inst < 2; ++inst) {
      const int u = inst * 256 + w * 64 + lane;
      const int row = u >> 2, kb = (u & 3) * 8;
      gload_lds16(A  + (size_t)(rowBase + row) * 1024 + k0 + kb, &As[(inst * 256 + w * 64) * 8]);
      gload_lds16(Bw + (size_t)(colBase + row) * 1024 + k0 + kb, &Bs[(inst * 256 + w * 64) * 8]);
    }
    __syncthreads();
    bf16x8 a[4], bb[4];
    #pragma unroll
    for (int i = 0; i < 4; ++i) a[i]  = *(const bf16x8*)&As[(wr * 64 + i * 16 + il) * 32 + 8 * g];
    #pragma unroll
    for (int j = 0; j < 4; ++j) bb[j] = *(const bf16x8*)&Bs[(wc * 64 + j * 16 + il) * 32 + 8 * g];
    #pragma unroll
    for (int i = 0; i < 4; ++i)
      #pragma unroll
      for (int j = 0; j < 4; ++j)
        acc[i][j] = __builtin_amdgcn_mfma_f32_16x16x32_bf16(a[i], bb[j], acc[i][j], 0, 0, 0);
  }

  // epilogue: route to Q (n<1024) or K (n>=1024), layout [b][h][row][d]
  #pragma unroll
  for (int i = 0; i < 4; ++i) {
    const int mbase = rowBase + wr * 64 + i * 16 + g * 4;
    #pragma unroll
    for (int j = 0; j < 4; ++j) {
      const int n = colBase + wc * 64 + j * 16 + il;
      const float bv = bias[n];
      #pragma unroll
      for (int r = 0; r < 4; ++r) {
        const int mg = mbase + r;
        const int brow = mg >> 10, nrow = mg & 1023;
        const float v = acc[i][j][r] + bv;
        if (n < 1024) {
          const int h = n >> 6, d = n & 63;
          Qg[(((size_t)(brow * 16 + h)) * 1024 + nrow) * 64 + d] = (bf16_t)v;
        } else {
          const int n2 = n - 1024;
          const int h = n2 >> 6, d = n2 & 63;
          Kg[(((size_t)(brow * 16 + h)) * 1024 + nrow) * 64 + d] = (bf16_t)v;
        }
      }
    }
  }
}

// ---------------- causal flash attention + tanh (swapped-operand, XOR-swizzled) ----------------
// grid (NN/64=16, NBH=128), block 256 (4 waves, 16 q-rows each)
// All LDS tiles are [64 rows][128 bytes], swizzle: byte ^= ((row&7)<<4).
__global__ __launch_bounds__(256) void flash_attn_k(
    const bf16_t* __restrict__ Qg, const bf16_t* __restrict__ Kg,
    const bf16_t* __restrict__ Vt, const float* __restrict__ temperature,
    float* __restrict__ out) {
  const int qb = (int)gridDim.x - 1 - (int)blockIdx.x;   // long blocks first
  const int bh = blockIdx.y;
  const int b = bh >> 4, h = bh & 15;
  __shared__ bf16_t QP[64 * 64];   // Q stage, then per-wave P tiles (w*1024)
  __shared__ bf16_t Ks[64 * 64];
  __shared__ bf16_t Vts[64 * 64];
  const int tid = threadIdx.x, w = tid >> 6, lane = tid & 63;
  const int il = lane & 15, g = lane >> 4;
  const int sw = (il & 7) << 4;    // per-lane XOR swizzle (row&7 == il&7 for all our rows)
  const float scale = 0.125f / temperature[h];

  // stage Q tile (64 rows x 128B), source pre-swizzled so linear LDS + XOR read works
  #pragma unroll
  for (int inst = 0; inst < 2; ++inst) {
    const int u = inst * 256 + w * 64 + lane;
    const int row = u >> 3, c = (u & 7) ^ (row & 7);
    gload_lds16(Qg + ((size_t)bh * 1024 + qb * 64 + row) * 64 + c * 8, &QP[u * 8]);
  }
  __syncthreads();
  const char* QPb = (const char*)QP;
  const int qrow_loc = w * 16 + il;
  bf16x8 qf0 = *(const bf16x8*)(QPb + qrow_loc * 128 + ((16 * g) ^ sw));
  bf16x8 qf1 = *(const bf16x8*)(QPb + qrow_loc * 128 + ((64 + 16 * g) ^ sw));

  const int qrow = qb * 64 + qrow_loc;       // this lane's q row (global)
  float m_run = -1e30f, l_run = 0.f;
  f32x4 acc[4];                              // acc[td][r] = O[q=qrow][d=td*16+g*4+r]
  #pragma unroll
  for (int td = 0; td < 4; ++td) acc[td] = (f32x4){0.f, 0.f, 0.f, 0.f};

  char* Pb = (char*)QP + w * 2048;           // per-wave P tile [16 rows][128B]
  const char* Kb = (const char*)Ks;
  const char* Vb = (const char*)Vts;

  for (int j = 0; j <= qb; ++j) {
    __syncthreads();
    #pragma unroll
    for (int inst = 0; inst < 2; ++inst) {
      const int u = inst * 256 + w * 64 + lane;
      const int row = u >> 3, c = (u & 7) ^ (row & 7);
      gload_lds16(Kg + ((size_t)bh * 1024 + j * 64 + row) * 64 + c * 8, &Ks[u * 8]);
      gload_lds16(Vt + (size_t)bh * (ND * NN) + (size_t)row * NN + j * 64 + c * 8, &Vts[u * 8]);
    }
    __syncthreads();

    // S^T tiles: s[t][r] = S[q = qrow][k = j*64 + t*16 + g*4 + r]
    f32x4 s[4];
    #pragma unroll
    for (int t = 0; t < 4; ++t) {
      const int krow = t * 16 + il;
      bf16x8 k0 = *(const bf16x8*)(Kb + krow * 128 + ((16 * g) ^ sw));
      bf16x8 k1 = *(const bf16x8*)(Kb + krow * 128 + ((64 + 16 * g) ^ sw));
      s[t] = (f32x4){0.f, 0.f, 0.f, 0.f};
      s[t] = __builtin_amdgcn_mfma_f32_16x16x32_bf16(k0, qf0, s[t], 0, 0, 0);
      s[t] = __builtin_amdgcn_mfma_f32_16x16x32_bf16(k1, qf1, s[t], 0, 0, 0);
    }

    float sv[16];
    #pragma unroll
    for (int t = 0; t < 4; ++t)
      #pragma unroll
      for (int r = 0; r < 4; ++r) sv[t * 4 + r] = s[t][r] * scale;
    if (j == qb) {   // diagonal tile: mask k > qrow
      #pragma unroll
      for (int t = 0; t < 4; ++t)
        #pragma unroll
        for (int r = 0; r < 4; ++r) {
          const int kg = j * 64 + t * 16 + g * 4 + r;
          if (kg > qrow) sv[t * 4 + r] = -1e30f;
        }
    }

    // row max: 15 local + 2 shfl (lanes il, il+16, il+32, il+48 share q-row)
    float mx = sv[0];
    #pragma unroll
    for (int i = 1; i < 16; ++i) mx = fmaxf(mx, sv[i]);
    mx = fmaxf(mx, __shfl_xor(mx, 16, 64));
    mx = fmaxf(mx, __shfl_xor(mx, 32, 64));
    const float mnew = fmaxf(m_run, mx);

    float p[16], lsum = 0.f;
    #pragma unroll
    for (int i = 0; i < 16; ++i) { p[i] = __expf(sv[i] - mnew); lsum += p[i]; }
    lsum += __shfl_xor(lsum, 16, 64);
    lsum += __shfl_xor(lsum, 32, 64);

    const float f = __expf(m_run - mnew);
    m_run = mnew;
    l_run = l_run * f + lsum;
    #pragma unroll
    for (int td = 0; td < 4; ++td) acc[td] *= f;

    // P -> LDS: row q=il, k = t*16+g*4+r contiguous in r -> packed b64, swizzled
    #pragma unroll
    for (int t = 0; t < 4; ++t) {
      bf16x4 pk;
      pk[0] = (bf16_t)p[t * 4 + 0]; pk[1] = (bf16_t)p[t * 4 + 1];
      pk[2] = (bf16_t)p[t * 4 + 2]; pk[3] = (bf16_t)p[t * 4 + 3];
      *(bf16x4*)(Pb + il * 128 + ((t * 32 + g * 8) ^ sw)) = pk;
    }

    bf16x8 pf0 = *(const bf16x8*)(Pb + il * 128 + ((16 * g) ^ sw));
    bf16x8 pf1 = *(const bf16x8*)(Pb + il * 128 + ((64 + 16 * g) ^ sw));
    #pragma unroll
    for (int td = 0; td < 4; ++td) {
      const int drow = td * 16 + il;
      bf16x8 v0 = *(const bf16x8*)(Vb + drow * 128 + ((16 * g) ^ sw));
      bf16x8 v1 = *(const bf16x8*)(Vb + drow * 128 + ((64 + 16 * g) ^ sw));
      acc[td] = __builtin_amdgcn_mfma_f32_16x16x32_bf16(v0, pf0, acc[td], 0, 0, 0);
      acc[td] = __builtin_amdgcn_mfma_f32_16x16x32_bf16(v1, pf1, acc[td], 0, 0, 0);
    }
  }

  // epilogue: out[q][h*64+d] = tanh(acc/l), float4 stores (d = td*16+g*4+r, r contiguous)
  const float inv = 1.0f / l_run;
  float* orow = out + ((size_t)b * 1024 + qrow) * 1024 + (h << 6);
  #pragma unroll
  for (int td = 0; td < 4; ++td) {
    float4 o;
    o.x = tanhf(acc[td][0] * inv);
    o.y = tanhf(acc[td][1] * inv);
    o.z = tanhf(acc[td][2] * inv);
    o.w = tanhf(acc[td][3] * inv);
    *(float4*)(orow + td * 16 + g * 4) = o;
  }
}

extern "C" void kernel_launch(void* const* d_in, const int* in_sizes, int n_in,
                              void* d_out, int out_size, void* d_ws, size_t ws_size,
                              hipStream_t stream) {
  const float* z_k  = (const float*)d_in[0];
  const float* x    = (const float*)d_in[1];
  const float* Wqkv = (const float*)d_in[2];
  const float* bqkv = (const float*)d_in[3];
  const float* temp = (const float*)d_in[4];
  float* out = (float*)d_out;

  char* ws = (char*)d_ws;
  // layout (bytes): A 16M, Bw 4M, Qg 16M, Kg 16M, Vt 16M  => 71.3 MB total
  bf16_t* A  = (bf16_t*)(ws);
  bf16_t* Bw = (bf16_t*)(ws + 16777216);
  bf16_t* Qg = (bf16_t*)(ws + 16777216 + 4194304);
  bf16_t* Kg = (bf16_t*)(ws + 16777216 + 4194304 + 16777216);
  bf16_t* Vt = (bf16_t*)(ws + 16777216 + 4194304 + 2 * 16777216);

  cast_f32_bf16_k<<<4096, 256, 0, stream>>>(z_k, A);          // 8192*1024
  cast_f32_bf16_k<<<1024, 256, 0, stream>>>(Wqkv, Bw);        // first 2048 rows
  build_vt_k<<<dim3(16, 128), 256, 0, stream>>>(x, Vt);
  gemm_qk_k<<<dim3(16, 64), 256, 0, stream>>>(A, Bw, bqkv, Qg, Kg);
  flash_attn_k<<<dim3(16, 128), 256, 0, stream>>>(Qg, Kg, Vt, temp, out);
}